// Round 1
// baseline (9074.418 us; speedup 1.0000x reference)
//
#include <hip/hip_runtime.h>
#include <math.h>

#define CI_STRIDE 262144   // 64*64*64
#define B_STRIDE  16777216 // 64*CI_STRIDE

// ---------------------------------------------------------------------------
// Kernel 1: build the 125 x 64ci x 64co conv weights into d_ws.
// Layout: Wg[((dxy*64 + ci)*5 + dz)*64 + co], dxy = dx*5+dy.
// Folds in the 0.1 conv scale, ALPHA factors, cos(pi d)/5^1.5 and sh1.
// ---------------------------------------------------------------------------
__global__ __launch_bounds__(256) void gen_w_kernel(const float* __restrict__ tp,
                                                    float* __restrict__ Wg) {
    const int t  = blockIdx.x;            // tap id 0..124
    const int dx = t / 25, dy = (t / 5) % 5, dz = t % 5;
    const float rx = -1.f + 0.5f * (float)dx;
    const float ry = -1.f + 0.5f * (float)dy;
    const float rz = -1.f + 0.5f * (float)dz;
    const float d    = sqrtf(rx * rx + ry * ry + rz * rz);
    const float invd = (d > 0.f) ? (1.f / d) : 0.f;
    const float SQRT3 = 1.7320508075688772f;
    // sh1 = sqrt(3) * unit[..., [1,2,0]]  (y, z, x components)
    const float sh1_0 = SQRT3 * ry * invd;
    const float sh1_1 = SQRT3 * rz * invd;
    const float sh1_2 = SQRT3 * rx * invd;
    float basis[5];
#pragma unroll
    for (int m = 0; m < 5; ++m) {
        float u = (d - 0.25f * (float)m) * 4.0f;   // (d - v_m)/sigma, sigma=0.25
        basis[m] = expf(-u * u) * (1.0f / 1.12f);
    }
    const float S  = cosf(3.14159265358979323846f * d) * (1.0f / 11.180339887498949f); // cos(pi d)/5^1.5
    const float fA = 0.1f * 0.17677669529663687f * S;                        // 0.1*ALPHA_0*S
    const float fB = 0.1f * 0.3061862178478972f * 0.5773502691896258f * S;   // 0.1*ALPHA_1*INV_SQRT3*S
    const float fC = 0.1f * 0.17677669529663687f * 0.5773502691896258f * S;  // 0.1*ALPHA_0*INV_SQRT3*S
    const float fD = fB;
    const int dxy = dx * 5 + dy;

    for (int e = threadIdx.x; e < 4096; e += 256) {
        const int ci = e >> 6, co = e & 63;
        int   tt;
        float f;
        if (ci < 16) {
            if (co < 16) {                       // k00: ALPHA_0 * wA
                tt = ci * 16 + co; f = fA;
            } else {                             // k01: ALPHA_1*INV_SQRT3 * wB[u,w]*sh1[kk]
                const int c = co - 16, w = c / 3, kk = c % 3;
                tt = 256 + ci * 16 + w;
                f  = fB * ((kk == 0) ? sh1_0 : (kk == 1) ? sh1_1 : sh1_2);
            }
        } else {
            const int a = ci - 16, uu = a / 3, ii = a % 3;
            const float s1i = (ii == 0) ? sh1_0 : (ii == 1) ? sh1_1 : sh1_2;
            if (co < 16) {                       // k10: ALPHA_0*INV_SQRT3 * wD[u,w]*sh1[ii]
                tt = 768 + uu * 16 + co; f = fC * s1i;
            } else {                             // k11: ALPHA_1*INV_SQRT3 * wC[u,w]*delta(ii,kk)
                const int c = co - 16, w = c / 3, kk = c % 3;
                tt = 512 + uu * 16 + w;
                f  = (ii == kk) ? fD : 0.0f;
            }
        }
        float E = 0.f;
#pragma unroll
        for (int m = 0; m < 5; ++m) E += basis[m] * tp[m * 1024 + tt];
        Wg[((size_t)(dxy * 64 + ci) * 5 + dz) * 64 + co] = f * E;
    }
}

// ---------------------------------------------------------------------------
// Kernel 2: direct conv + fused sc. One block per (b, x, y): 64co x 64z tile.
// Per (dx,dy): stage input row (64ci x 68z, zero halo) in LDS, then
// acc[4co][4z] += W[co,ci,dx,dy,dz] * xs[ci][z+dz].  sc fused at center tap.
// ---------------------------------------------------------------------------
__global__ __launch_bounds__(256) void conv_kernel(const float* __restrict__ x,
                                                   const float* __restrict__ lw0,
                                                   const float* __restrict__ lw1,
                                                   const float* __restrict__ Wg,
                                                   float* __restrict__ out) {
    __shared__ float xs[64 * 68];  // row-major [ci][68], index z+2 holds input z
    const int tid = threadIdx.x;
    const int tz  = tid & 15, z0  = tz * 4;
    const int tco = tid >> 4, co0 = tco * 4;   // wave-uniform co0<16 split
    const int bid = blockIdx.x;
    const int b = bid >> 12, bx = (bid >> 6) & 63, by = bid & 63;

    float acc[4][4];
#pragma unroll
    for (int cc = 0; cc < 4; ++cc)
#pragma unroll
        for (int zz = 0; zz < 4; ++zz) acc[cc][zz] = 0.f;

    if (tid < 64) {  // zero halo once; barriers in the first iteration cover visibility
        xs[tid * 68 + 0]  = 0.f; xs[tid * 68 + 1]  = 0.f;
        xs[tid * 68 + 66] = 0.f; xs[tid * 68 + 67] = 0.f;
    }

    const float* xb = x + (size_t)b * B_STRIDE;

    for (int dxy = 0; dxy < 25; ++dxy) {
        const int dx = dxy / 5, dy = dxy % 5;
        const int xx = bx + dx - 2, yy = by + dy - 2;
        if (xx < 0 || xx >= 64 || yy < 0 || yy >= 64) continue;  // block-uniform skip
        __syncthreads();
        {
            const float* xrow = xb + (size_t)xx * 4096 + (size_t)yy * 64;
#pragma unroll
            for (int r = 0; r < 4; ++r) {
                const int ci = (tid >> 4) + r * 16;
                const float4 v = *(const float4*)(xrow + (size_t)ci * CI_STRIDE + z0);
                float* dst = &xs[ci * 68 + 2 + z0];          // 8B-aligned: use float2 pair
                *(float2*)(dst)     = make_float2(v.x, v.y);
                *(float2*)(dst + 2) = make_float2(v.z, v.w);
            }
        }
        __syncthreads();

        const float* wp0 = Wg + (size_t)dxy * 20480 + co0;   // dxy*64*320
        for (int ci = 0; ci < 64; ++ci) {
            const float4 xlo = *(const float4*)&xs[ci * 68 + z0];      // input z0-2..z0+1
            const float4 xhi = *(const float4*)&xs[ci * 68 + z0 + 4];  // input z0+2..z0+5
            const float xv[8] = {xlo.x, xlo.y, xlo.z, xlo.w, xhi.x, xhi.y, xhi.z, xhi.w};
            const float* wp = wp0 + (size_t)ci * 320;
#pragma unroll
            for (int dz = 0; dz < 5; ++dz) {
                const float4 wv = *(const float4*)(wp + dz * 64);
                const float wvv[4] = {wv.x, wv.y, wv.z, wv.w};
#pragma unroll
                for (int cc = 0; cc < 4; ++cc) {
#pragma unroll
                    for (int zz = 0; zz < 4; ++zz)
                        acc[cc][zz] = fmaf(wvv[cc], xv[zz + dz], acc[cc][zz]);
                }
            }
        }

        if (dxy == 12) {  // xs holds the center row (bx,by): fuse sc (wave-uniform branch)
            if (co0 < 16) {
#pragma unroll
                for (int u = 0; u < 16; ++u) {
                    const float* xr = &xs[u * 68 + 2 + z0];
                    const float x0v = xr[0], x1v = xr[1], x2v = xr[2], x3v = xr[3];
#pragma unroll
                    for (int cc = 0; cc < 4; ++cc) {
                        const float w = 0.25f * lw0[u * 16 + co0 + cc];
                        acc[cc][0] = fmaf(w, x0v, acc[cc][0]);
                        acc[cc][1] = fmaf(w, x1v, acc[cc][1]);
                        acc[cc][2] = fmaf(w, x2v, acc[cc][2]);
                        acc[cc][3] = fmaf(w, x3v, acc[cc][3]);
                    }
                }
            } else {
#pragma unroll
                for (int cc = 0; cc < 4; ++cc) {
                    const int c = co0 + cc - 16;
                    const int wdx = c / 3, ii = c % 3;
#pragma unroll
                    for (int u = 0; u < 16; ++u) {
                        const float w = 0.25f * lw1[u * 16 + wdx];
                        const float* xr = &xs[(16 + u * 3 + ii) * 68 + 2 + z0];
                        acc[cc][0] = fmaf(w, xr[0], acc[cc][0]);
                        acc[cc][1] = fmaf(w, xr[1], acc[cc][1]);
                        acc[cc][2] = fmaf(w, xr[2], acc[cc][2]);
                        acc[cc][3] = fmaf(w, xr[3], acc[cc][3]);
                    }
                }
            }
        }
    }

    const size_t ob = (size_t)b * B_STRIDE + (size_t)bx * 4096 + (size_t)by * 64 + z0;
#pragma unroll
    for (int cc = 0; cc < 4; ++cc) {
        *(float4*)&out[ob + (size_t)(co0 + cc) * CI_STRIDE] =
            make_float4(acc[cc][0], acc[cc][1], acc[cc][2], acc[cc][3]);
    }
}

extern "C" void kernel_launch(void* const* d_in, const int* in_sizes, int n_in,
                              void* d_out, int out_size, void* d_ws, size_t ws_size,
                              hipStream_t stream) {
    const float* x   = (const float*)d_in[0];  // (2, 64, 64, 64, 64)
    const float* lw0 = (const float*)d_in[1];  // (16, 16)
    const float* lw1 = (const float*)d_in[2];  // (16, 16)
    const float* tp  = (const float*)d_in[3];  // (5, 1024)
    float* out = (float*)d_out;
    float* Wg  = (float*)d_ws;                 // 125*64*64*4 B = 2.05 MB

    gen_w_kernel<<<125, 256, 0, stream>>>(tp, Wg);
    conv_kernel<<<8192, 256, 0, stream>>>(x, lw0, lw1, Wg, out);
}

// Round 2
// 676.865 us; speedup vs baseline: 13.4065x; 13.4065x over previous
//
#include <hip/hip_runtime.h>
#include <hip/hip_bf16.h>
#include <math.h>

typedef __bf16 bf16x8 __attribute__((ext_vector_type(8)));
typedef float  f32x4  __attribute__((ext_vector_type(4)));

#define CI_STRIDE 262144   // 64*64*64
#define Z2  68             // z' extent (z + 2-halo each side)
#define CIP 72             // ci padded leading dim (16B-aligned rows, balanced banks)

// ---------------------------------------------------------------------------
// Kernel 1: build bf16 weights Wb[t][co][ci] (A-operand layout: m=co, k=ci).
// Folds 0.1 conv scale, ALPHA factors, cos(pi d)/5^1.5, sh1; center tap (t=62)
// additionally absorbs the block-diagonal pointwise mix sc (0.25*lin_w).
// ---------------------------------------------------------------------------
__global__ __launch_bounds__(256) void gen_w(const float* __restrict__ tp,
                                             const float* __restrict__ lw0,
                                             const float* __restrict__ lw1,
                                             __bf16* __restrict__ Wb) {
    const int t  = blockIdx.x;            // tap id 0..124, t = dx*25+dy*5+dz
    const int dx = t / 25, dy = (t / 5) % 5, dz = t % 5;
    const float rx = -1.f + 0.5f * (float)dx;
    const float ry = -1.f + 0.5f * (float)dy;
    const float rz = -1.f + 0.5f * (float)dz;
    const float d    = sqrtf(rx * rx + ry * ry + rz * rz);
    const float invd = (d > 0.f) ? (1.f / d) : 0.f;
    const float SQRT3 = 1.7320508075688772f;
    const float sh1_0 = SQRT3 * ry * invd;   // sh1 = sqrt(3)*unit[[1,2,0]]
    const float sh1_1 = SQRT3 * rz * invd;
    const float sh1_2 = SQRT3 * rx * invd;
    float basis[5];
#pragma unroll
    for (int m = 0; m < 5; ++m) {
        float u = (d - 0.25f * (float)m) * 4.0f;
        basis[m] = expf(-u * u) * (1.0f / 1.12f);
    }
    const float S  = cosf(3.14159265358979323846f * d) * (1.0f / 11.180339887498949f);
    const float fA = 0.1f * 0.17677669529663687f * S;
    const float fB = 0.1f * 0.3061862178478972f * 0.5773502691896258f * S;
    const float fC = 0.1f * 0.17677669529663687f * 0.5773502691896258f * S;
    const float fD = fB;

    for (int e = threadIdx.x; e < 4096; e += 256) {
        const int co = e >> 6, ci = e & 63;   // write coalesced in ci
        int   tt;
        float f;
        if (ci < 16) {
            if (co < 16) { tt = ci * 16 + co; f = fA; }
            else {
                const int c = co - 16, w = c / 3, kk = c % 3;
                tt = 256 + ci * 16 + w;
                f  = fB * ((kk == 0) ? sh1_0 : (kk == 1) ? sh1_1 : sh1_2);
            }
        } else {
            const int a = ci - 16, uu = a / 3, ii = a % 3;
            const float s1i = (ii == 0) ? sh1_0 : (ii == 1) ? sh1_1 : sh1_2;
            if (co < 16) { tt = 768 + uu * 16 + co; f = fC * s1i; }
            else {
                const int c = co - 16, w = c / 3, kk = c % 3;
                tt = 512 + uu * 16 + w;
                f  = (ii == kk) ? fD : 0.0f;
            }
        }
        float E = 0.f;
#pragma unroll
        for (int m = 0; m < 5; ++m) E += basis[m] * tp[m * 1024 + tt];
        float val = f * E;
        if (t == 62) {  // fold sc into the center tap
            if (ci < 16 && co < 16) {
                val += 0.25f * lw0[ci * 16 + co];
            } else if (ci >= 16 && co >= 16) {
                const int a = co - 16, bq = ci - 16;
                const int wq = a / 3, iq = a % 3, uq = bq / 3, iiq = bq % 3;
                if (iq == iiq) val += 0.25f * lw1[uq * 16 + wq];
            }
        }
        Wb[(size_t)t * 4096 + e] = (__bf16)val;
    }
}

// ---------------------------------------------------------------------------
// Stage 12 input rows (y' = y0-2..y0+9) for plane x' = xc+dx-2 into LDS,
// layout xs[row][z'][ci] (z-major, ci contiguous -> serves MFMA B-fragments).
// Lane l covers z = l (coalesced 256B global reads), writes z' = l+2.
// ---------------------------------------------------------------------------
__device__ __forceinline__ void stage_rows(const float* __restrict__ x, __bf16* xs,
                                           int b, int xc, int y0, int dx, int w, int l) {
    const int xp  = xc + dx - 2;
    const bool xok = (xp >= 0) && (xp < 64);
    for (int rr = w; rr < 12; rr += 8) {
        const int yp = y0 + rr - 2;
        const bool ok = xok && (yp >= 0) && (yp < 64);
        const float* src = x + (size_t)b * 64 * CI_STRIDE + (size_t)xp * 4096 + yp * 64 + l;
        __bf16* dst = xs + ((size_t)rr * Z2 + 2 + l) * CIP;
        if (ok) {
#pragma unroll
            for (int c8 = 0; c8 < 8; ++c8) {
                bf16x8 pk;
#pragma unroll
                for (int jj = 0; jj < 8; ++jj)
                    pk[jj] = (__bf16)src[(size_t)(c8 * 8 + jj) * CI_STRIDE];
                *(bf16x8*)(dst + c8 * 8) = pk;
            }
        } else {
            bf16x8 zz;
#pragma unroll
            for (int jj = 0; jj < 8; ++jj) zz[jj] = (__bf16)0.f;
#pragma unroll
            for (int c8 = 0; c8 < 8; ++c8) *(bf16x8*)(dst + c8 * 8) = zz;
        }
    }
}

// ---------------------------------------------------------------------------
// Kernel 2: implicit-GEMM conv. Block = 512 thr (8 waves) = (b, x, y-oct).
// Wave w: y = y0+w, M=64 co x N=64 z as 4x4 MFMA tiles; K = 64ci per tap,
// 125 taps. Weights double-buffered in LDS, prefetched one tap ahead.
// ---------------------------------------------------------------------------
__global__ __launch_bounds__(512, 2) void conv_mfma(const float* __restrict__ x,
                                                    const __bf16* __restrict__ Wb,
                                                    float* __restrict__ out) {
    __shared__ __align__(16) __bf16 xs[12 * Z2 * CIP];   // 117,504 B
    __shared__ __align__(16) __bf16 ws[2][64 * CIP];     //  18,432 B
    const int tid = threadIdx.x;
    const int l = tid & 63, w = tid >> 6;
    const int q = l >> 4, i16 = l & 15;
    const int b  = blockIdx.x >> 9;
    const int xc = (blockIdx.x >> 3) & 63;
    const int y0 = (blockIdx.x & 7) << 3;

    f32x4 acc[4][4];
#pragma unroll
    for (int mt = 0; mt < 4; ++mt)
#pragma unroll
        for (int nt = 0; nt < 4; ++nt) acc[mt][nt] = (f32x4)(0.f);

    // zero the z-halo columns z' in {0,1,66,67} once (never rewritten)
    for (int idx = tid; idx < 12 * 4 * CIP; idx += 512) {
        const int r = idx / (4 * CIP), rem = idx % (4 * CIP);
        const int zs = rem / CIP, ci = rem % CIP;
        const int zp = (zs < 2) ? zs : (64 + zs);
        xs[((size_t)r * Z2 + zp) * CIP + ci] = (__bf16)0.f;
    }

    stage_rows(x, xs, b, xc, y0, 0, w, l);

    // stage W[tap 0]
    uint4 wreg = ((const uint4*)Wb)[tid];
    *(uint4*)((__bf16*)ws[0] + (tid >> 3) * CIP + (tid & 7) * 8) = wreg;
    __syncthreads();

    for (int t = 0; t < 125; ++t) {
        const int p = t & 1;
        if (t < 124) wreg = ((const uint4*)Wb)[(size_t)(t + 1) * 512 + tid];  // L2-hit prefetch
        const int dy = (t / 5) % 5, dz = t % 5;
        const __bf16* xb = xs + ((size_t)(w + dy) * Z2 + dz + i16) * CIP + q * 8;
        const __bf16* wb = (const __bf16*)ws[p] + i16 * CIP + q * 8;
        bf16x8 A[4][2], B[4][2];
#pragma unroll
        for (int nt = 0; nt < 4; ++nt) {
            B[nt][0] = *(const bf16x8*)(xb + nt * 16 * CIP);
            B[nt][1] = *(const bf16x8*)(xb + nt * 16 * CIP + 32);
        }
#pragma unroll
        for (int mt = 0; mt < 4; ++mt) {
            A[mt][0] = *(const bf16x8*)(wb + mt * 16 * CIP);
            A[mt][1] = *(const bf16x8*)(wb + mt * 16 * CIP + 32);
        }
#pragma unroll
        for (int mt = 0; mt < 4; ++mt)
#pragma unroll
            for (int nt = 0; nt < 4; ++nt) {
                acc[mt][nt] = __builtin_amdgcn_mfma_f32_16x16x32_bf16(A[mt][0], B[nt][0], acc[mt][nt], 0, 0, 0);
                acc[mt][nt] = __builtin_amdgcn_mfma_f32_16x16x32_bf16(A[mt][1], B[nt][1], acc[mt][nt], 0, 0, 0);
            }
        if (t < 124)
            *(uint4*)((__bf16*)ws[1 - p] + (tid >> 3) * CIP + (tid & 7) * 8) = wreg;
        __syncthreads();   // publishes W[t+1]; fences xs restage below
        if ((t % 25) == 24 && t < 124) {
            stage_rows(x, xs, b, xc, y0, t / 25 + 1, w, l);
            __syncthreads();
        }
    }

    // epilogue: D layout col=lane&15 (z), row=quad*4+j (co-local)
    const size_t obase = (size_t)b * 64 * CI_STRIDE + (size_t)xc * 4096 + (size_t)(y0 + w) * 64;
#pragma unroll
    for (int mt = 0; mt < 4; ++mt)
#pragma unroll
        for (int j = 0; j < 4; ++j) {
            const int co = mt * 16 + q * 4 + j;
            float* op = out + obase + (size_t)co * CI_STRIDE + i16;
#pragma unroll
            for (int nt = 0; nt < 4; ++nt) op[nt * 16] = acc[mt][nt][j];
        }
}

extern "C" void kernel_launch(void* const* d_in, const int* in_sizes, int n_in,
                              void* d_out, int out_size, void* d_ws, size_t ws_size,
                              hipStream_t stream) {
    (void)in_sizes; (void)n_in; (void)out_size; (void)ws_size;
    const float* x   = (const float*)d_in[0];  // (2, 64, 64, 64, 64) fp32
    const float* lw0 = (const float*)d_in[1];  // (16, 16)
    const float* lw1 = (const float*)d_in[2];  // (16, 16)
    const float* tp  = (const float*)d_in[3];  // (5, 1024)
    float* out = (float*)d_out;
    __bf16* Wb = (__bf16*)d_ws;                // 125*4096*2 B = 1.0 MB

    gen_w<<<125, 256, 0, stream>>>(tp, lw0, lw1, Wb);
    conv_mfma<<<1024, 512, 0, stream>>>(x, Wb, out);
}

// Round 3
// 573.492 us; speedup vs baseline: 15.8231x; 1.1803x over previous
//
#include <hip/hip_runtime.h>
#include <hip/hip_bf16.h>
#include <math.h>

typedef __bf16 bf16x8 __attribute__((ext_vector_type(8)));
typedef __bf16 bf16x2 __attribute__((ext_vector_type(2)));
typedef float  f32x4  __attribute__((ext_vector_type(4)));

#define CI_STRIDE 262144   // 64*64*64
#define B_STRIDE  16777216 // 64*CI_STRIDE
#define Z2 68              // z' extent (64 + 2 halo each side)
#define CP 40              // padded ci-half leading dim (32 data + 8 pad; 80 B rows)

// ---------------------------------------------------------------------------
// Kernel 1: bf16 weights, layout Wb[t][h][co][ci32]  (h = ci-half).
// Folds 0.1 conv scale, ALPHA factors, cos(pi d)/5^1.5, sh1; center tap t=62
// absorbs the block-diagonal pointwise mix sc (0.25*lin_w).
// ---------------------------------------------------------------------------
__global__ __launch_bounds__(256) void gen_w(const float* __restrict__ tp,
                                             const float* __restrict__ lw0,
                                             const float* __restrict__ lw1,
                                             __bf16* __restrict__ Wb) {
    const int t  = blockIdx.x;            // tap id 0..124, t = dx*25+dy*5+dz
    const int dx = t / 25, dy = (t / 5) % 5, dz = t % 5;
    const float rx = -1.f + 0.5f * (float)dx;
    const float ry = -1.f + 0.5f * (float)dy;
    const float rz = -1.f + 0.5f * (float)dz;
    const float d    = sqrtf(rx * rx + ry * ry + rz * rz);
    const float invd = (d > 0.f) ? (1.f / d) : 0.f;
    const float SQRT3 = 1.7320508075688772f;
    const float sh1_0 = SQRT3 * ry * invd;   // sh1 = sqrt(3)*unit[[1,2,0]]
    const float sh1_1 = SQRT3 * rz * invd;
    const float sh1_2 = SQRT3 * rx * invd;
    float basis[5];
#pragma unroll
    for (int m = 0; m < 5; ++m) {
        float u = (d - 0.25f * (float)m) * 4.0f;
        basis[m] = expf(-u * u) * (1.0f / 1.12f);
    }
    const float S  = cosf(3.14159265358979323846f * d) * (1.0f / 11.180339887498949f);
    const float fA = 0.1f * 0.17677669529663687f * S;
    const float fB = 0.1f * 0.3061862178478972f * 0.5773502691896258f * S;
    const float fC = 0.1f * 0.17677669529663687f * 0.5773502691896258f * S;
    const float fD = fB;

    for (int e = threadIdx.x; e < 4096; e += 256) {
        const int co = e >> 6, ci = e & 63;
        int   tt;
        float f;
        if (ci < 16) {
            if (co < 16) { tt = ci * 16 + co; f = fA; }
            else {
                const int c = co - 16, w = c / 3, kk = c % 3;
                tt = 256 + ci * 16 + w;
                f  = fB * ((kk == 0) ? sh1_0 : (kk == 1) ? sh1_1 : sh1_2);
            }
        } else {
            const int a = ci - 16, uu = a / 3, ii = a % 3;
            const float s1i = (ii == 0) ? sh1_0 : (ii == 1) ? sh1_1 : sh1_2;
            if (co < 16) { tt = 768 + uu * 16 + co; f = fC * s1i; }
            else {
                const int c = co - 16, w = c / 3, kk = c % 3;
                tt = 512 + uu * 16 + w;
                f  = (ii == kk) ? fD : 0.0f;
            }
        }
        float E = 0.f;
#pragma unroll
        for (int m = 0; m < 5; ++m) E += basis[m] * tp[m * 1024 + tt];
        float val = f * E;
        if (t == 62) {  // fold sc into the center tap
            if (ci < 16 && co < 16) {
                val += 0.25f * lw0[ci * 16 + co];
            } else if (ci >= 16 && co >= 16) {
                const int a = co - 16, bq = ci - 16;
                const int wq = a / 3, iq = a % 3, uq = bq / 3, iiq = bq % 3;
                if (iq == iiq) val += 0.25f * lw1[uq * 16 + wq];
            }
        }
        // layout: Wb[((t*2 + h)*64 + co)*32 + ci_lo]
        Wb[((size_t)(t * 2 + (ci >> 5)) * 64 + co) * 32 + (ci & 31)] = (__bf16)val;
    }
}

// ---------------------------------------------------------------------------
// Kernel 2: implicit-GEMM conv. Block = 512 thr (8 waves) = (b, x, 16-y grp).
// Wave w: 2 y-rows (2w, 2w+1), M=64 co x N=128 (2y x 64z), K split in two
// ci-32 passes. A-fragments loaded per-lane from global (L1-broadcast,
// register-prefetched one tap ahead) -> no per-tap barrier.
// ---------------------------------------------------------------------------
__global__ __launch_bounds__(512, 2) void conv_mfma(const float* __restrict__ x,
                                                    const __bf16* __restrict__ Wb,
                                                    float* __restrict__ out) {
    __shared__ __align__(16) __bf16 xs[20 * Z2 * CP];   // 108,800 B
    const int tid = threadIdx.x;
    const int l = tid & 63, w = tid >> 6;
    const int q = l >> 4, i16 = l & 15;
    const int b  = blockIdx.x >> 8;
    const int xc = (blockIdx.x >> 2) & 63;
    const int y0 = (blockIdx.x & 3) << 4;

    f32x4 acc[4][8];
#pragma unroll
    for (int mt = 0; mt < 4; ++mt)
#pragma unroll
        for (int nt = 0; nt < 8; ++nt) acc[mt][nt] = (f32x4)(0.f);

    // zero the z-halo columns z' in {0,1,66,67} (staging never writes them)
    for (int idx = tid; idx < 20 * 4 * CP; idx += 512) {
        const int r = idx / (4 * CP), rem = idx % (4 * CP);
        const int zs = rem / CP, ci = rem % CP;
        const int zp = (zs < 2) ? zs : (64 + zs);
        xs[((size_t)r * Z2 + zp) * CP + ci] = (__bf16)0.f;
    }

    const float* xb = x + (size_t)b * B_STRIDE;

    // preload A-fragments for s=0 (h=0, t=0): co = mt*16+i16, k = q*8+j
    bf16x8 Acur[4], Anext[4];
#pragma unroll
    for (int mt = 0; mt < 4; ++mt)
        Acur[mt] = *(const bf16x8*)(Wb + ((size_t)(mt * 16 + i16)) * 32 + q * 8);

    for (int h = 0; h < 2; ++h) {
        for (int dx = 0; dx < 5; ++dx) {
            __syncthreads();   // all waves done reading the previous plane
            {   // stage plane x' = xc+dx-2, rows y' = y0-2 .. y0+17, ci-half h
                const int xp = xc + dx - 2;
                const bool xok = (xp >= 0) && (xp < 64);
                for (int r = w; r < 20; r += 8) {
                    const int yp = y0 + r - 2;
                    const bool ok = xok && (yp >= 0) && (yp < 64);
                    const float* src = xb + (size_t)(h * 32) * CI_STRIDE
                                     + (size_t)xp * 4096 + yp * 64 + l;
                    __bf16* dst = xs + ((size_t)r * Z2 + 2 + l) * CP;
                    if (ok) {
#pragma unroll
                        for (int ci = 0; ci < 32; ci += 2) {
                            const float a0 = src[(size_t)ci * CI_STRIDE];
                            const float a1 = src[(size_t)(ci + 1) * CI_STRIDE];
                            bf16x2 pk = {(__bf16)a0, (__bf16)a1};
                            *(bf16x2*)(dst + ci) = pk;
                        }
                    } else {
                        bf16x2 zz = {(__bf16)0.f, (__bf16)0.f};
#pragma unroll
                        for (int ci = 0; ci < 32; ci += 2) *(bf16x2*)(dst + ci) = zz;
                    }
                }
            }
            __syncthreads();

            for (int dydz = 0; dydz < 25; ++dydz) {
                const int t = dx * 25 + dydz;
                const int s = h * 125 + t;
                // prefetch A for s+1 (sequence: h-major, t ascending)
                {
                    const int sn = (s < 249) ? (s + 1) : s;
                    const int hn = sn / 125, tn = sn % 125;
                    const __bf16* wp = Wb + ((size_t)(tn * 2 + hn) * 64 + i16) * 32 + q * 8;
#pragma unroll
                    for (int mt = 0; mt < 4; ++mt)
                        Anext[mt] = *(const bf16x8*)(wp + (size_t)mt * 16 * 32);
                }
                const int dy = dydz / 5, dz = dydz % 5;
                const __bf16* bbase = xs + ((size_t)(2 * w + dy) * Z2 + dz + i16) * CP + q * 8;
                bf16x8 Bf[8];
#pragma unroll
                for (int yy = 0; yy < 2; ++yy)
#pragma unroll
                    for (int zt = 0; zt < 4; ++zt)
                        Bf[yy * 4 + zt] = *(const bf16x8*)(bbase + (size_t)(yy * Z2 + zt * 16) * CP);
#pragma unroll
                for (int mt = 0; mt < 4; ++mt)
#pragma unroll
                    for (int nt = 0; nt < 8; ++nt)
                        acc[mt][nt] = __builtin_amdgcn_mfma_f32_16x16x32_bf16(
                            Acur[mt], Bf[nt], acc[mt][nt], 0, 0, 0);
#pragma unroll
                for (int mt = 0; mt < 4; ++mt) Acur[mt] = Anext[mt];
            }
        }
    }

    // epilogue: D layout col(n)=lane&15, row(m)=q*4+j
    const size_t ob = (size_t)b * B_STRIDE + (size_t)xc * 4096;
#pragma unroll
    for (int mt = 0; mt < 4; ++mt)
#pragma unroll
        for (int j = 0; j < 4; ++j) {
            const int co = mt * 16 + q * 4 + j;
            float* op = out + ob + (size_t)co * CI_STRIDE;
#pragma unroll
            for (int nt = 0; nt < 8; ++nt) {
                const int y = y0 + 2 * w + (nt >> 2);
                const int z = (nt & 3) * 16 + i16;
                op[y * 64 + z] = acc[mt][nt][j];
            }
        }
}

extern "C" void kernel_launch(void* const* d_in, const int* in_sizes, int n_in,
                              void* d_out, int out_size, void* d_ws, size_t ws_size,
                              hipStream_t stream) {
    (void)in_sizes; (void)n_in; (void)out_size; (void)ws_size;
    const float* x   = (const float*)d_in[0];  // (2, 64, 64, 64, 64) fp32
    const float* lw0 = (const float*)d_in[1];  // (16, 16)
    const float* lw1 = (const float*)d_in[2];  // (16, 16)
    const float* tp  = (const float*)d_in[3];  // (5, 1024)
    float* out = (float*)d_out;
    __bf16* Wb = (__bf16*)d_ws;                // 125*2*64*32*2 B = 1.0 MB

    gen_w<<<125, 256, 0, stream>>>(tp, lw0, lw1, Wb);
    conv_mfma<<<512, 512, 0, stream>>>(x, Wb, out);
}